// Round 5
// baseline (61.094 us; speedup 1.0000x reference)
//
#include <hip/hip_runtime.h>
#include <hip/hip_bf16.h>
#include <math.h>

typedef __bf16 bf16;
typedef __attribute__((ext_vector_type(4))) float f32x4;
typedef __attribute__((ext_vector_type(8))) bf16 bf16x8;
typedef __attribute__((ext_vector_type(4))) bf16 bf16x4;

#define M_TOT 16384
#define K_TOT 1024
#define E_TOT 1024   // 512 mu + 512 logvar
#define D_EMB 512
#define NTILES 16    // K_TOT / 64

// ============================================================
// Pass 1: fused f32 -> bf16 convert of x, W_mu, W_logvar
// ============================================================
__global__ __launch_bounds__(256) void cvt_all(
    const float* __restrict__ x, const float* __restrict__ wmu,
    const float* __restrict__ wlv, bf16* __restrict__ xb, bf16* __restrict__ wb)
{
    const int NX8 = (M_TOT * K_TOT) / 8;   // 2097152
    const int NW8 = (D_EMB * K_TOT) / 8;   // 65536
    const int TOT = NX8 + 2 * NW8;
    int i = blockIdx.x * blockDim.x + threadIdx.x;
    const int stride = gridDim.x * blockDim.x;
    for (; i < TOT; i += stride) {
        const float* s;
        bf16* d;
        if (i < NX8)            { s = x   + (size_t)i * 8;          d = xb + (size_t)i * 8; }
        else if (i < NX8 + NW8) { s = wmu + (size_t)(i - NX8) * 8;  d = wb + (size_t)(i - NX8) * 8; }
        else                    { s = wlv + (size_t)(i - NX8 - NW8) * 8; d = wb + (size_t)(i - NX8) * 8; }
        f32x4 a = ((const f32x4*)s)[0];
        f32x4 b = ((const f32x4*)s)[1];
        bf16x8 o;
        o[0] = (bf16)a[0]; o[1] = (bf16)a[1]; o[2] = (bf16)a[2]; o[3] = (bf16)a[3];
        o[4] = (bf16)b[0]; o[5] = (bf16)b[1]; o[6] = (bf16)b[2]; o[7] = (bf16)b[3];
        *(bf16x8*)d = o;
    }
}

// ============================================================
// Pass 2: 256x256 tile, BK=64, 8 waves, 8-phase counted-vmcnt
// schedule (T3+T4) + LDS XOR swizzle (T2) + setprio (T5) +
// bijective XCD swizzle (T1).
// LDS: [2 buf][2 op][256 rows][64 elems] bf16 = 131072 B.
// Swizzle: LDS(row, c) holds global(row, c ^ ((row&7)<<3)) [elems];
// inverse applied on global source (global_load_lds dest stays linear).
// Phase/region ledger (per K-tile t):
//   ph0 reads A-h0(8)+B-h0(4); stages (t+1, A-h1)
//   ph1 reads B-h1(4);         stages (t+2, A-h0)
//   ph2 reads A-h1(8);         stages (t+2, B-h0)
//   ph3 reads none;            stages (t+2, B-h1)
// Each region read in exactly one phase; its overwrite (for t+2) is
// issued >=1 barrier after that phase. vmcnt(6) at tile end drains
// exactly tile t+1 (3 halves of t+2 stay in flight). MFMA clusters
// ordered kk-outer / m-inner: dependent MFMAs 8 apart.
// ============================================================
__global__ __launch_bounds__(512, 2) void gpe_gemm8(
    const bf16* __restrict__ xb,     // [16384][1024]
    const bf16* __restrict__ Wb,     // [1024][1024]
    const float* __restrict__ b_mu,
    const float* __restrict__ b_logvar,
    float* __restrict__ out)         // [2][16384][512]
{
    __shared__ __align__(16) bf16 lds[2 * 2 * 256 * 64];   // 131072 B

    const int tid  = threadIdx.x;
    const int lane = tid & 63;
    const int wid  = tid >> 6;        // 0..7
    const int wr   = wid >> 2;        // 0..1
    const int wc   = wid & 3;         // 0..3

    // T1: bijective XCD swizzle (nwg=256, 32/XCD); bn inner per XCD.
    const int bid = blockIdx.x;
    const int swz = (bid & 7) * 32 + (bid >> 3);
    const int bn  = swz & 3;          // 0..3
    const int bm  = swz >> 2;         // 0..63

    const bf16* __restrict__ Ap = xb + (size_t)(bm * 256) * K_TOT;
    const bf16* __restrict__ Bp = Wb + (size_t)(bn * 256) * K_TOT;

    // staging constants (per thread): linear LDS dest, inverse-swizzled src.
    const int srow = wid * 8 + (lane >> 3);                   // 0..63
    const int scol = ((lane & 7) ^ (lane >> 3)) << 3;         // elems
    const int sdst = wid * 512;                               // elems

    // read constants
    const int fr    = lane & 15;
    const int g16   = lane >> 4;
    const int colk0 = (g16 * 8) ^ ((fr & 7) << 3);            // elems; kk=1 -> ^32
    const int rA    = wr * 16 + fr;                           // + m*32
    const int rB    = wc * 16 + fr;                           // + n*64

    f32x4 acc[8][4];
#pragma unroll
    for (int m = 0; m < 8; ++m)
#pragma unroll
        for (int n = 0; n < 4; ++n)
            acc[m][n] = (f32x4){0.f, 0.f, 0.f, 0.f};

    // stage one half-tile into buffer `sbuf`: h = 0:A-h0 1:A-h1 2:B-h0 3:B-h1
    auto stage = [&](int tile, int sbuf, int h) {
        if (tile >= NTILES) return;
        const int op = h >> 1, hh = h & 1;
        const bf16* base = op ? Bp : Ap;
#pragma unroll
        for (int q = 0; q < 2; ++q) {
            const bf16* s = base + (size_t)(hh * 128 + q * 64 + srow) * K_TOT + tile * 64 + scol;
            bf16* d = lds + sbuf * 32768 + op * 16384 + hh * 8192 + q * 4096 + sdst;
            __builtin_amdgcn_global_load_lds(
                (const __attribute__((address_space(1))) void*)s,
                (__attribute__((address_space(3))) void*)d, 16, 0, 0);
        }
    };

    // ---- prologue: tile0 all halves (8 loads); tile1 h0,h2,h3 (6 loads) ----
    stage(0, 0, 0); stage(0, 0, 1); stage(0, 0, 2); stage(0, 0, 3);
    stage(1, 1, 0); stage(1, 1, 2); stage(1, 1, 3);
    asm volatile("s_waitcnt vmcnt(6)" ::: "memory");   // drains tile0's 8
    __builtin_amdgcn_s_barrier();

#define TILE_BODY(T, BUF)                                                            \
    {                                                                                \
        const int t = (T);                                                           \
        const bf16* Ab = lds + (BUF) * 32768;                                        \
        const bf16* Bb = Ab + 16384;                                                 \
        bf16x8 af[4][2], bv[4][2];                                                   \
        /* ---- phase 0: B-h0 (4 rd) + A-h0 (8 rd); stage (t+1, A-h1) ---- */        \
        _Pragma("unroll")                                                            \
        for (int n = 0; n < 2; ++n) {                                                \
            bv[n][0] = *(const bf16x8*)&Bb[(n * 64 + rB) * 64 + colk0];              \
            bv[n][1] = *(const bf16x8*)&Bb[(n * 64 + rB) * 64 + (colk0 ^ 32)];       \
        }                                                                            \
        _Pragma("unroll")                                                            \
        for (int m = 0; m < 4; ++m) {                                                \
            af[m][0] = *(const bf16x8*)&Ab[(m * 32 + rA) * 64 + colk0];              \
            af[m][1] = *(const bf16x8*)&Ab[(m * 32 + rA) * 64 + (colk0 ^ 32)];       \
        }                                                                            \
        stage(t + 1, (BUF) ^ 1, 1);                                                  \
        asm volatile("s_waitcnt lgkmcnt(8)" ::: "memory");                           \
        __builtin_amdgcn_s_barrier();                                                \
        asm volatile("s_waitcnt lgkmcnt(0)" ::: "memory");                           \
        __builtin_amdgcn_s_setprio(1);                                               \
        _Pragma("unroll")                                                            \
        for (int kk = 0; kk < 2; ++kk)                                               \
            _Pragma("unroll")                                                        \
            for (int n = 0; n < 2; ++n)                                              \
                _Pragma("unroll")                                                    \
                for (int m = 0; m < 4; ++m)                                          \
                    acc[m][n] = __builtin_amdgcn_mfma_f32_16x16x32_bf16(             \
                        af[m][kk], bv[n][kk], acc[m][n], 0, 0, 0);                   \
        __builtin_amdgcn_s_setprio(0);                                               \
        __builtin_amdgcn_s_barrier();                                                \
        /* ---- phase 1: B-h1 (4 rd); stage (t+2, A-h0) ---- */                      \
        _Pragma("unroll")                                                            \
        for (int n = 2; n < 4; ++n) {                                                \
            bv[n][0] = *(const bf16x8*)&Bb[(n * 64 + rB) * 64 + colk0];              \
            bv[n][1] = *(const bf16x8*)&Bb[(n * 64 + rB) * 64 + (colk0 ^ 32)];       \
        }                                                                            \
        stage(t + 2, (BUF), 0);                                                      \
        __builtin_amdgcn_s_barrier();                                                \
        asm volatile("s_waitcnt lgkmcnt(0)" ::: "memory");                           \
        __builtin_amdgcn_s_setprio(1);                                               \
        _Pragma("unroll")                                                            \
        for (int kk = 0; kk < 2; ++kk)                                               \
            _Pragma("unroll")                                                        \
            for (int n = 2; n < 4; ++n)                                              \
                _Pragma("unroll")                                                    \
                for (int m = 0; m < 4; ++m)                                          \
                    acc[m][n] = __builtin_amdgcn_mfma_f32_16x16x32_bf16(             \
                        af[m][kk], bv[n][kk], acc[m][n], 0, 0, 0);                   \
        __builtin_amdgcn_s_setprio(0);                                               \
        __builtin_amdgcn_s_barrier();                                                \
        /* ---- phase 2: A-h1 (8 rd, overwrite af); stage (t+2, B-h0) ---- */        \
        _Pragma("unroll")                                                            \
        for (int m = 0; m < 4; ++m) {                                                \
            af[m][0] = *(const bf16x8*)&Ab[((m + 4) * 32 + rA) * 64 + colk0];        \
            af[m][1] = *(const bf16x8*)&Ab[((m + 4) * 32 + rA) * 64 + (colk0 ^ 32)]; \
        }                                                                            \
        stage(t + 2, (BUF), 2);                                                      \
        __builtin_amdgcn_s_barrier();                                                \
        asm volatile("s_waitcnt lgkmcnt(0)" ::: "memory");                           \
        __builtin_amdgcn_s_setprio(1);                                               \
        _Pragma("unroll")                                                            \
        for (int kk = 0; kk < 2; ++kk)                                               \
            _Pragma("unroll")                                                        \
            for (int n = 2; n < 4; ++n)                                              \
                _Pragma("unroll")                                                    \
                for (int m = 0; m < 4; ++m)                                          \
                    acc[m + 4][n] = __builtin_amdgcn_mfma_f32_16x16x32_bf16(         \
                        af[m][kk], bv[n][kk], acc[m + 4][n], 0, 0, 0);               \
        __builtin_amdgcn_s_setprio(0);                                               \
        __builtin_amdgcn_s_barrier();                                                \
        /* ---- phase 3: stage (t+2, B-h1); MFMA m4-7 x n0-1 ---- */                 \
        stage(t + 2, (BUF), 3);                                                      \
        __builtin_amdgcn_s_barrier();                                                \
        __builtin_amdgcn_s_setprio(1);                                               \
        _Pragma("unroll")                                                            \
        for (int kk = 0; kk < 2; ++kk)                                               \
            _Pragma("unroll")                                                        \
            for (int n = 0; n < 2; ++n)                                              \
                _Pragma("unroll")                                                    \
                for (int m = 0; m < 4; ++m)                                          \
                    acc[m + 4][n] = __builtin_amdgcn_mfma_f32_16x16x32_bf16(         \
                        af[m][kk], bv[n][kk], acc[m + 4][n], 0, 0, 0);               \
        __builtin_amdgcn_s_setprio(0);                                               \
        if (t + 2 < NTILES)      asm volatile("s_waitcnt vmcnt(6)" ::: "memory");    \
        else if (t + 1 < NTILES) asm volatile("s_waitcnt vmcnt(0)" ::: "memory");    \
        __builtin_amdgcn_s_barrier();                                                \
    }

    for (int t0 = 0; t0 < NTILES; t0 += 2) {
        TILE_BODY(t0, 0)
        TILE_BODY(t0 + 1, 1)
    }
#undef TILE_BODY

    // ---- epilogue: bias (+ exp for logvar head) ----
    const bool is_mu = (bn < 2);
    const float* __restrict__ bias = is_mu ? b_mu : b_logvar;
    const int cb = (bn & 1) * 256;
    float* __restrict__ obase = is_mu ? out : (out + (size_t)M_TOT * D_EMB);

#pragma unroll
    for (int m = 0; m < 8; ++m) {
        const int row0 = bm * 256 + m * 32 + wr * 16 + g16 * 4;
#pragma unroll
        for (int n = 0; n < 4; ++n) {
            const int c = cb + n * 64 + wc * 16 + fr;
            const float bvs = bias[c];
#pragma unroll
            for (int j = 0; j < 4; ++j) {
                float v = acc[m][n][j] + bvs;
                if (!is_mu) v = __expf(0.5f * v);
                obase[(size_t)(row0 + j) * D_EMB + c] = v;
            }
        }
    }
}

// ============================================================
// Fallback: single-pass f32-staging GEMM (no workspace needed)
// ============================================================
#define LDS_STRIDE 40
__global__ __launch_bounds__(256) void gpe_gemm_fb(
    const float* __restrict__ x, const float* __restrict__ W_mu,
    const float* __restrict__ b_mu, const float* __restrict__ W_logvar,
    const float* __restrict__ b_logvar, float* __restrict__ out)
{
    __shared__ __align__(16) bf16 As[128][LDS_STRIDE];
    __shared__ __align__(16) bf16 Bs[128][LDS_STRIDE];
    const int tid = threadIdx.x, lane = tid & 63, wid = tid >> 6;
    const int wr = wid >> 1, wc = wid & 1;
    const int bn = blockIdx.x & 7, bm = blockIdx.x >> 3;
    const int ebase = bn * 128;
    const bool is_mu = (ebase < D_EMB);
    const float* Wp = is_mu ? (W_mu + (size_t)ebase * K_TOT)
                            : (W_logvar + (size_t)(ebase - D_EMB) * K_TOT);
    const float* bias = is_mu ? b_mu : b_logvar;
    const int cbase = is_mu ? ebase : (ebase - D_EMB);
    float* obase = is_mu ? out : (out + (size_t)M_TOT * D_EMB);
    const float* Ap = x + (size_t)(bm * 128) * K_TOT;
    f32x4 acc[4][4];
#pragma unroll
    for (int m = 0; m < 4; ++m)
#pragma unroll
        for (int n = 0; n < 4; ++n) acc[m][n] = (f32x4){0.f, 0.f, 0.f, 0.f};
    const int fr = lane & 15, fk = (lane >> 4) * 8;
    const int arow = wr * 64 + fr, brow = wc * 64 + fr;
    for (int kt = 0; kt < K_TOT / 32; ++kt) {
        const int k0 = kt * 32;
#pragma unroll
        for (int s = 0; s < 4; ++s) {
            const int idx = s * 256 + tid;
            const int row = idx >> 3, col = (idx & 7) << 2;
            f32x4 va = *reinterpret_cast<const f32x4*>(Ap + (size_t)row * K_TOT + k0 + col);
            f32x4 vb = *reinterpret_cast<const f32x4*>(Wp + (size_t)row * K_TOT + k0 + col);
            bf16x4 ha, hb;
#pragma unroll
            for (int j = 0; j < 4; ++j) { ha[j] = (bf16)va[j]; hb[j] = (bf16)vb[j]; }
            *reinterpret_cast<bf16x4*>(&As[row][col]) = ha;
            *reinterpret_cast<bf16x4*>(&Bs[row][col]) = hb;
        }
        __syncthreads();
        bf16x8 af[4], bfv[4];
#pragma unroll
        for (int m = 0; m < 4; ++m)
            af[m] = *reinterpret_cast<const bf16x8*>(&As[arow + m * 16][fk]);
#pragma unroll
        for (int n = 0; n < 4; ++n)
            bfv[n] = *reinterpret_cast<const bf16x8*>(&Bs[brow + n * 16][fk]);
#pragma unroll
        for (int m = 0; m < 4; ++m)
#pragma unroll
            for (int n = 0; n < 4; ++n)
                acc[m][n] = __builtin_amdgcn_mfma_f32_16x16x32_bf16(af[m], bfv[n], acc[m][n], 0, 0, 0);
        __syncthreads();
    }
#pragma unroll
    for (int m = 0; m < 4; ++m) {
        const int rbase = bm * 128 + wr * 64 + m * 16 + (lane >> 4) * 4;
#pragma unroll
        for (int n = 0; n < 4; ++n) {
            const int c = cbase + wc * 64 + n * 16 + (lane & 15);
            const float bv = bias[c];
#pragma unroll
            for (int j = 0; j < 4; ++j) {
                float v = acc[m][n][j] + bv;
                if (!is_mu) v = __expf(0.5f * v);
                obase[(size_t)(rbase + j) * D_EMB + c] = v;
            }
        }
    }
}

extern "C" void kernel_launch(void* const* d_in, const int* in_sizes, int n_in,
                              void* d_out, int out_size, void* d_ws, size_t ws_size,
                              hipStream_t stream) {
    const float* x        = (const float*)d_in[0];
    const float* W_mu     = (const float*)d_in[1];
    const float* b_mu     = (const float*)d_in[2];
    const float* W_logvar = (const float*)d_in[3];
    const float* b_logvar = (const float*)d_in[4];
    float* out = (float*)d_out;

    const size_t n_x = (size_t)M_TOT * K_TOT;
    const size_t n_w = (size_t)D_EMB * K_TOT;
    const size_t ws_needed = (n_x + 2 * n_w) * sizeof(bf16);

    if (ws_size >= ws_needed) {
        bf16* xb = (bf16*)d_ws;
        bf16* Wb = xb + n_x;
        cvt_all<<<2048, 256, 0, stream>>>(x, W_mu, W_logvar, xb, Wb);
        gpe_gemm8<<<256, 512, 0, stream>>>(xb, Wb, b_mu, b_logvar, out);
    } else {
        gpe_gemm_fb<<<1024, 256, 0, stream>>>(x, W_mu, b_mu, W_logvar, b_logvar, out);
    }
}

// Round 6
// 51.982 us; speedup vs baseline: 1.1753x; 1.1753x over previous
//
#include <hip/hip_runtime.h>
#include <hip/hip_bf16.h>
#include <math.h>

typedef __bf16 bf16;
typedef __attribute__((ext_vector_type(4))) float f32x4;
typedef __attribute__((ext_vector_type(8))) bf16 bf16x8;

#define M_TOT 16384
#define K_TOT 1024
#define D_EMB 512
#define NT 32          // K_TOT / BK, BK = 32

// ============================================================
// Single fused kernel: C[16384,1024] = x_f32 . W_f32^T (both heads),
// bf16 MFMA with in-register f32->bf16 conversion during staging.
//   tile 256x256, BK=32, 8 waves (2M x 4N), per-wave out 128x64.
//   LDS [2 buf][A|B][256 rows][32 elems] bf16 = 64 KiB, double-buffered.
//   Reg-staging (global f32 -> reg -> cvt -> swizzled ds_write) replaces
//   global_load_lds; counted vmcnt(4) keeps a 2-tile-deep load pipeline.
//   Swizzle (both sides): 8-elem slot index s ^= (row>>1)&3. Verified
//   bank-balanced: frag ds_read_b128 and staging ds_write_b128 both land
//   8 lanes per bank (the wave64-b128 minimum -> 0 conflicts).
// Ledger (per tile t, buf=t&1, nbuf=buf^1; A(t+1)/B(t+1) f32 already
// in regs, issued during tile t-1):
//   ph0: vmcnt(4) [drains A(t+1); B(t+1) stays]; cvt+write A(t+1)->nbuf;
//        issue gloadA(t+2); ds_read bv[0..3],af[0..3] from buf;
//        lgkm(0); barrier; 16 MFMA (m0-3 x n0-3).
//   ph1: vmcnt(4 if t+2<NT else 0) [drains B(t+1)]; cvt+write B(t+1);
//        issue gloadB(t+2); ds_read af2[0..3]; lgkm(0); barrier;
//        16 MFMA (m4-7 x n0-3).
// WAR: nbuf regions written in ph0/ph1(t) were last read in ph0/ph1(t-1),
// whose reads completed before that phase's barrier (each wave does
// lgkm(0) before arriving). Visibility: writes drain via the writer's own
// lgkm(0) before its barrier -> all waves see tile t+1 data at ph0(t+1).
// ============================================================
__global__ __launch_bounds__(512, 2) void gpe_fused(
    const float* __restrict__ x,
    const float* __restrict__ W_mu,
    const float* __restrict__ W_logvar,
    const float* __restrict__ b_mu,
    const float* __restrict__ b_logvar,
    float* __restrict__ out)         // [2][16384][512]
{
    __shared__ __align__(16) bf16 lds[2 * 2 * 256 * 32];   // 65536 B

    const int tid  = threadIdx.x;
    const int lane = tid & 63;
    const int wid  = tid >> 6;        // 0..7
    const int wr   = wid >> 2;        // 0..1
    const int wc   = wid & 3;         // 0..3

    // T1: bijective XCD swizzle (grid 256 = 8 XCD x 32); bn inner per XCD.
    const int bid = blockIdx.x;
    const int swz = (bid & 7) * 32 + (bid >> 3);
    const int bn  = swz & 3;          // 0..3
    const int bm  = swz >> 2;         // 0..63

    // ---- staging geometry: thread owns half a row (16 f32) per op ----
    const int r_l  = tid >> 1;                       // 0..255
    const int half = tid & 1;
    const float* __restrict__ Asrc = x + (size_t)(bm * 256 + r_l) * K_TOT + half * 16;
    const float* __restrict__ Wrow = (bn < 2)
        ? (W_mu     + (size_t)(bn * 256)       * K_TOT)
        : (W_logvar + (size_t)((bn - 2) * 256) * K_TOT);
    const float* __restrict__ Bsrc = Wrow + (size_t)r_l * K_TOT + half * 16;

    // swizzled ds_write elem offsets (slot ^= (row>>1)&3)
    const int wxor  = (r_l >> 1) & 3;
    const int woff0 = r_l * 32 + ((half * 2 + 0) ^ wxor) * 8;
    const int woff1 = r_l * 32 + ((half * 2 + 1) ^ wxor) * 8;

    // frag read geometry (same swizzle)
    const int fr  = lane & 15;
    const int g16 = lane >> 4;                       // slot index 0..3
    const int rsl = (g16 ^ ((fr >> 1) & 3)) * 8;     // swizzled elem col
    const int rA  = wr * 16 + fr;                    // + m*32
    const int rB  = wc * 16 + fr;                    // + n*64

    f32x4 acc[8][4];
#pragma unroll
    for (int m = 0; m < 8; ++m)
#pragma unroll
        for (int n = 0; n < 4; ++n)
            acc[m][n] = (f32x4){0.f, 0.f, 0.f, 0.f};

    f32x4 regA[4], regB[4];

    auto gloadA = [&](int t) {
#pragma unroll
        for (int j = 0; j < 4; ++j)
            regA[j] = *(const f32x4*)(Asrc + t * 32 + j * 4);
    };
    auto gloadB = [&](int t) {
#pragma unroll
        for (int j = 0; j < 4; ++j)
            regB[j] = *(const f32x4*)(Bsrc + t * 32 + j * 4);
    };
    // cvt 16 f32 -> 2x bf16x8, swizzled ds_write into op region base (elems)
    auto cwA = [&](bf16* opbase) {
        bf16x8 w0, w1;
#pragma unroll
        for (int j = 0; j < 4; ++j) {
            w0[j]     = (bf16)regA[0][j];
            w0[j + 4] = (bf16)regA[1][j];
            w1[j]     = (bf16)regA[2][j];
            w1[j + 4] = (bf16)regA[3][j];
        }
        *(bf16x8*)&opbase[woff0] = w0;
        *(bf16x8*)&opbase[woff1] = w1;
    };
    auto cwB = [&](bf16* opbase) {
        bf16x8 w0, w1;
#pragma unroll
        for (int j = 0; j < 4; ++j) {
            w0[j]     = (bf16)regB[0][j];
            w0[j + 4] = (bf16)regB[1][j];
            w1[j]     = (bf16)regB[2][j];
            w1[j + 4] = (bf16)regB[3][j];
        }
        *(bf16x8*)&opbase[woff0] = w0;
        *(bf16x8*)&opbase[woff1] = w1;
    };

    // ---- prologue: tile0 -> buf0 (through regs), tile1 -> regs ----
    gloadA(0); gloadB(0);
    asm volatile("s_waitcnt vmcnt(0)" ::: "memory");
    cwA(lds);                 // buf0 A region
    cwB(lds + 8192);          // buf0 B region
    gloadA(1); gloadB(1);
    asm volatile("s_waitcnt lgkmcnt(0)" ::: "memory");
    __builtin_amdgcn_s_barrier();

    for (int t = 0; t < NT; ++t) {
        const int buf = t & 1;
        bf16* Ab = lds + buf * 16384;
        bf16* Bb = Ab + 8192;
        bf16* Abn = lds + (buf ^ 1) * 16384;
        bf16* Bbn = Abn + 8192;

        // ---------------- phase 0 ----------------
        if (t + 1 < NT) {
            asm volatile("s_waitcnt vmcnt(4)" ::: "memory");   // A(t+1) arrived
            cwA(Abn);
            if (t + 2 < NT) gloadA(t + 2);
        }
        bf16x8 bv[4], af[4];
#pragma unroll
        for (int n = 0; n < 4; ++n)
            bv[n] = *(const bf16x8*)&Bb[(n * 64 + rB) * 32 + rsl];
#pragma unroll
        for (int m = 0; m < 4; ++m)
            af[m] = *(const bf16x8*)&Ab[(m * 32 + rA) * 32 + rsl];
        asm volatile("s_waitcnt lgkmcnt(0)" ::: "memory");
        __builtin_amdgcn_s_barrier();
        __builtin_amdgcn_s_setprio(1);
#pragma unroll
        for (int n = 0; n < 4; ++n)
#pragma unroll
            for (int m = 0; m < 4; ++m)
                acc[m][n] = __builtin_amdgcn_mfma_f32_16x16x32_bf16(af[m], bv[n], acc[m][n], 0, 0, 0);
        __builtin_amdgcn_s_setprio(0);

        // ---------------- phase 1 ----------------
        if (t + 1 < NT) {
            if (t + 2 < NT) asm volatile("s_waitcnt vmcnt(4)" ::: "memory");  // B(t+1) arrived
            else            asm volatile("s_waitcnt vmcnt(0)" ::: "memory");
            cwB(Bbn);
            if (t + 2 < NT) gloadB(t + 2);
        }
        bf16x8 af2[4];
#pragma unroll
        for (int m = 0; m < 4; ++m)
            af2[m] = *(const bf16x8*)&Ab[((m + 4) * 32 + rA) * 32 + rsl];
        asm volatile("s_waitcnt lgkmcnt(0)" ::: "memory");
        __builtin_amdgcn_s_barrier();
        __builtin_amdgcn_s_setprio(1);
#pragma unroll
        for (int n = 0; n < 4; ++n)
#pragma unroll
            for (int m = 0; m < 4; ++m)
                acc[m + 4][n] = __builtin_amdgcn_mfma_f32_16x16x32_bf16(af2[m], bv[n], acc[m + 4][n], 0, 0, 0);
        __builtin_amdgcn_s_setprio(0);
    }

    // ---- epilogue: bias (+ exp for logvar head) ----
    const bool is_mu = (bn < 2);
    const float* __restrict__ bias = is_mu ? b_mu : b_logvar;
    const int cb = (bn & 1) * 256;
    float* __restrict__ obase = is_mu ? out : (out + (size_t)M_TOT * D_EMB);

#pragma unroll
    for (int m = 0; m < 8; ++m) {
        const int row0 = bm * 256 + m * 32 + wr * 16 + g16 * 4;
#pragma unroll
        for (int n = 0; n < 4; ++n) {
            const int c = cb + n * 64 + wc * 16 + fr;
            const float bvs = bias[c];
#pragma unroll
            for (int j = 0; j < 4; ++j) {
                float v = acc[m][n][j] + bvs;
                if (!is_mu) v = __expf(0.5f * v);
                obase[(size_t)(row0 + j) * D_EMB + c] = v;
            }
        }
    }
}

extern "C" void kernel_launch(void* const* d_in, const int* in_sizes, int n_in,
                              void* d_out, int out_size, void* d_ws, size_t ws_size,
                              hipStream_t stream) {
    const float* x        = (const float*)d_in[0];
    const float* W_mu     = (const float*)d_in[1];
    const float* b_mu     = (const float*)d_in[2];
    const float* W_logvar = (const float*)d_in[3];
    const float* b_logvar = (const float*)d_in[4];
    float* out = (float*)d_out;

    gpe_fused<<<256, 512, 0, stream>>>(x, W_mu, W_logvar, b_mu, b_logvar, out);
}